// Round 2
// baseline (174.270 us; speedup 1.0000x reference)
//
#include <hip/hip_runtime.h>

typedef __bf16 bf16x8 __attribute__((ext_vector_type(8)));
typedef float  f32x4  __attribute__((ext_vector_type(4)));
typedef unsigned short u16;

#define NB    512
#define SEQ   128
#define EMB   300
#define NU    320               // unified N (300 filters padded)
#define NT_TOT 20               // N tiles of 16
#define KT_TOT 50               // K = 1600 = 50*32 (5 rows x 320 cols)
#define WU_ELEMS (NU * 1600)    // 512000 bf16
#define OFF_FEATS (WU_ELEMS * 2)  // feats: 512*300 f32 after weights

__device__ __forceinline__ u16 f2bf(float f) {
  unsigned u = __builtin_bit_cast(unsigned, f);
  return (u16)((u + 0x7fffu + ((u >> 16) & 1u)) >> 16);   // RNE
}

// Unified weights, MFMA-B-fragment order, kt-major:
//   elem idx = ((kt*20 + nt)*64 + lane)*8 + j
//   -> W[f = nt*16 + (lane&15)][kk = kt*32 + (lane>>4)*8 + j]
// kk -> (dk = kk/320, e = kk%320); window row dk aligned to k=5 (rows s-2..s+2):
//   f<100: w3 valid dk 2..4 ; f<200: w4 valid dk 1..4 ; f<300: w5 dk 0..4
__global__ void prep_weights(const float* __restrict__ w3, const float* __restrict__ w4,
                             const float* __restrict__ w5, u16* __restrict__ wu) {
  int idx = blockIdx.x * blockDim.x + threadIdx.x;
  if (idx >= WU_ELEMS) return;
  int j = idx & 7, l = (idx >> 3) & 63, t = idx >> 9;
  int nt = t % NT_TOT, kt = t / NT_TOT;
  int f  = nt * 16 + (l & 15);
  int kk = kt * 32 + ((l >> 4) << 3) + j;
  int dk = kk / 320, e = kk - dk * 320;
  float v = 0.f;
  if (f < 300 && e < 300) {
    if (f < 100)      { if (dk >= 2) v = w3[(f * 3 + dk - 2) * 300 + e]; }
    else if (f < 200) { if (dk >= 1) v = w4[((f - 100) * 4 + dk - 1) * 300 + e]; }
    else              {              v = w5[((f - 200) * 5 + dk) * 300 + e]; }
  }
  wu[idx] = f2bf(v);
}

// Block = (sample b, N-half nh): M=128, N=160, K=1600 (2 E-phases of 160 cols).
// 4 waves: (wm,wn) 2x2; wave = 4 M-tiles x 5 N-tiles, acc 80 VGPR.
__global__ __launch_bounds__(256, 3)
void conv_max_kernel(const float* __restrict__ x, const u16* __restrict__ wu,
                     const float* __restrict__ b3, const float* __restrict__ b4,
                     const float* __restrict__ b5, float* __restrict__ feats) {
  __shared__ __align__(16) u16 xs[132 * 160];   // rows -2..129, 160 cols/phase, stride 320B
  const int bid0 = blockIdx.x;
  const int bid  = (bid0 & 7) * 128 + (bid0 >> 3);   // XCD-contiguous chunks (1024%8==0)
  const int b = bid >> 1, nh = bid & 1;
  const int tid = threadIdx.x;
  const int l = tid & 63, w = tid >> 6;
  const int lo = l & 15, hi = l >> 4;
  const int wm = w >> 1, wn = w & 1;
  const int ntb = nh * 10 + wn * 5;
  const float* xb = x + (size_t)b * (SEQ * EMB);

  f32x4 acc[4][5];
  #pragma unroll
  for (int i = 0; i < 4; ++i)
    #pragma unroll
    for (int j = 0; j < 5; ++j) acc[i][j] = (f32x4){0.f, 0.f, 0.f, 0.f};

  // A-frag: lane reads xs row r = wm*64 + i*16 + lo + dk, byte = r*320 + k2*64 + hi*16
  // swizzle XOR ((r&7)<<4) with r&7 == (lo+dk)&7
  const int abase = (wm * 64 + lo) * 320 + hi * 16;

  for (int p = 0; p < 2; ++p) {
    if (p) __syncthreads();                       // phase-0 compute done before restage
    {   // stage x cols [p*160, p*160+160) as bf16, zero-padded rows/cols, swizzled
      const int e0 = p * 160;
      for (int t = tid; t < 132 * 40; t += 256) {
        int r = t / 40, cg = t - r * 40;
        int xr = r - 2, col = e0 + cg * 4;
        float4 v = make_float4(0.f, 0.f, 0.f, 0.f);
        if (xr >= 0 && xr < SEQ && col < 300)
          v = *reinterpret_cast<const float4*>(xb + xr * 300 + col);
        ushort4 h;
        h.x = f2bf(v.x); h.y = f2bf(v.y); h.z = f2bf(v.z); h.w = f2bf(v.w);
        int boff = (r * 320 + cg * 8) ^ ((r & 7) << 4);
        *reinterpret_cast<ushort4*>((char*)xs + boff) = h;
      }
    }
    __syncthreads();

    // kt(T) = (T/5)*10 + p*5 + (T%5), T in [0,25)
    const u16* wbp = wu + ((size_t)(p * 5) * NT_TOT + ntb) * 512 + l * 8;
    bf16x8 a[4], bA[5], bB[5];

#define LOADB(B, T) {                                                          \
    const u16* _pk = wbp + ((T) / 5) * (10 * NT_TOT * 512)                     \
                         + ((T) % 5) * (NT_TOT * 512);                         \
    _Pragma("unroll") for (int j = 0; j < 5; ++j)                              \
      B[j] = *reinterpret_cast<const bf16x8*>(_pk + j * 512); }

#define LOADA(T) {                                                             \
    _Pragma("unroll") for (int i = 0; i < 4; ++i) {                            \
      int boff = (abase + i * (16 * 320) + ((T) / 5) * 320 + ((T) % 5) * 64)   \
                 ^ (((lo + (T) / 5) & 7) << 4);                                \
      a[i] = *reinterpret_cast<const bf16x8*>((const char*)xs + boff); } }

#define MFMAS(B) {                                                             \
    _Pragma("unroll") for (int i = 0; i < 4; ++i)                              \
    _Pragma("unroll") for (int j = 0; j < 5; ++j)                              \
      acc[i][j] = __builtin_amdgcn_mfma_f32_16x16x32_bf16(a[i], B[j],          \
                                                          acc[i][j], 0, 0, 0); }

    LOADB(bA, 0);
    #pragma unroll
    for (int tt = 0; tt < 12; ++tt) {
      LOADA(2 * tt);
      LOADB(bB, 2 * tt + 1);
      MFMAS(bA);
      LOADA(2 * tt + 1);
      LOADB(bA, 2 * tt + 2);                      // tt==11 -> T=24 (last)
      MFMAS(bB);
    }
    LOADA(24);
    MFMAS(bA);
#undef LOADB
#undef LOADA
#undef MFMAS
  }

  // epilogue: bias + relu + masked max over this block's 128 s-positions
  #pragma unroll
  for (int j = 0; j < 5; ++j) {
    int f = (ntb + j) * 16 + lo;
    if (f < 300) {
      float bia  = (f < 100) ? b3[f] : (f < 200) ? b4[f - 100] : b5[f - 200];
      int   sval = (f < 100) ? 126   : (f < 200) ? 127         : 128;
      float cmax = 0.f;                            // relu floor
      #pragma unroll
      for (int i = 0; i < 4; ++i)
        #pragma unroll
        for (int ii = 0; ii < 4; ++ii) {
          int s = wm * 64 + i * 16 + hi * 4 + ii;  // C/D: row = (l>>4)*4+ii, col = l&15
          float v = acc[i][j][ii] + bia;
          if (s < sval) cmax = fmaxf(cmax, v);
        }
      cmax = fmaxf(cmax, __shfl_xor(cmax, 16));
      cmax = fmaxf(cmax, __shfl_xor(cmax, 32));
      if (hi == 0)
        atomicMax((int*)&feats[b * 300 + f], __float_as_int(fmaxf(cmax, 0.f)));
    }
  }
}

// feats[512,300] @ Wfc[5,300]^T + bfc -> log_softmax. One wave per row.
__global__ void fc_kernel(const float* __restrict__ feats, const float* __restrict__ Wfc,
                          const float* __restrict__ bfc, float* __restrict__ out) {
  const int b = blockIdx.x, l = threadIdx.x;
  float acc[5] = {0.f, 0.f, 0.f, 0.f, 0.f};
  for (int e = l; e < 300; e += 64) {
    float fv = feats[b * 300 + e];
    #pragma unroll
    for (int c = 0; c < 5; ++c) acc[c] += fv * Wfc[c * 300 + e];
  }
  #pragma unroll
  for (int off = 32; off; off >>= 1) {
    #pragma unroll
    for (int c = 0; c < 5; ++c) acc[c] += __shfl_down(acc[c], off);
  }
  if (l == 0) {
    float lg[5], m = -1e30f;
    #pragma unroll
    for (int c = 0; c < 5; ++c) { lg[c] = acc[c] + bfc[c]; m = fmaxf(m, lg[c]); }
    float se = 0.f;
    #pragma unroll
    for (int c = 0; c < 5; ++c) se += expf(lg[c] - m);
    float ls = logf(se);
    #pragma unroll
    for (int c = 0; c < 5; ++c) out[b * 5 + c] = lg[c] - m - ls;
  }
}

extern "C" void kernel_launch(void* const* d_in, const int* in_sizes, int n_in,
                              void* d_out, int out_size, void* d_ws, size_t ws_size,
                              hipStream_t stream) {
  const float* x   = (const float*)d_in[0];
  const float* w3  = (const float*)d_in[1];
  const float* b3  = (const float*)d_in[2];
  const float* w4  = (const float*)d_in[3];
  const float* b4  = (const float*)d_in[4];
  const float* w5  = (const float*)d_in[5];
  const float* b5  = (const float*)d_in[6];
  const float* Wfc = (const float*)d_in[7];
  const float* bfc = (const float*)d_in[8];
  float* out = (float*)d_out;

  u16*   wu    = (u16*)d_ws;
  float* feats = (float*)((char*)d_ws + OFF_FEATS);

  hipMemsetAsync(feats, 0, NB * 300 * sizeof(float), stream);  // atomicMax target

  prep_weights<<<(WU_ELEMS + 255) / 256, 256, 0, stream>>>(w3, w4, w5, wu);
  conv_max_kernel<<<NB * 2, 256, 0, stream>>>(x, wu, b3, b4, b5, feats);
  fc_kernel<<<NB, 64, 0, stream>>>(feats, Wfc, bfc, out);
}

// Round 3
// 100.962 us; speedup vs baseline: 1.7261x; 1.7261x over previous
//
#include <hip/hip_runtime.h>

typedef __bf16 bf16x8 __attribute__((ext_vector_type(8)));
typedef float  f32x4  __attribute__((ext_vector_type(4)));
typedef unsigned short u16;

#define NB    512
#define SEQ   128
#define EMB   300
#define NT_TOT 20               // N = 320 unified (300 filters padded), tiles of 16
#define WU_ELEMS (320 * 1600)   // 512000 bf16
#define OFF_FEATS (WU_ELEMS * 2)  // feats: 512*300 f32 after weights

__device__ __forceinline__ u16 f2bf(float f) {
  unsigned u = __builtin_bit_cast(unsigned, f);
  return (u16)((u + 0x7fffu + ((u >> 16) & 1u)) >> 16);   // RNE
}

// Unified weights, MFMA-B-fragment order, kt-major:
//   elem idx = ((kt*20 + nt)*64 + lane)*8 + j
//   -> W[f = nt*16 + (lane&15)][kk = kt*32 + (lane>>4)*8 + j]
// kk -> (dk = kk/320, e = kk%320); window rows aligned to k=5 (x rows s-2..s+2):
//   f<100: w3 valid dk 2..4 ; f<200: w4 valid dk 1..4 ; f<300: w5 dk 0..4
__global__ void prep_weights(const float* __restrict__ w3, const float* __restrict__ w4,
                             const float* __restrict__ w5, u16* __restrict__ wu) {
  int idx = blockIdx.x * blockDim.x + threadIdx.x;
  if (idx >= WU_ELEMS) return;
  int j = idx & 7, l = (idx >> 3) & 63, t = idx >> 9;
  int nt = t % NT_TOT, kt = t / NT_TOT;
  int f  = nt * 16 + (l & 15);
  int kk = kt * 32 + ((l >> 4) << 3) + j;
  int dk = kk / 320, e = kk - dk * 320;
  float v = 0.f;
  if (f < 300 && e < 300) {
    if (f < 100)      { if (dk >= 2) v = w3[(f * 3 + dk - 2) * 300 + e]; }
    else if (f < 200) { if (dk >= 1) v = w4[((f - 100) * 4 + dk - 1) * 300 + e]; }
    else              {              v = w5[((f - 200) * 5 + dk) * 300 + e]; }
  }
  wu[idx] = f2bf(v);
}

// Block = (sample b, s-half): M=64 outputs, N=320, K=1600. Round-1 LDS geometry
// (68 rows x 320 cols, 640 B stride, swizzle verified conflict-free), staged once.
// 4 waves as 2x2: wave (wm,wn) owns M-tiles {wm*2, wm*2+1}, N-tiles {wn*10..+9}.
// Per K-step: 2 ds_read_b128 (A) + 10 coalesced global b128 (B) + 20 MFMA.
__global__ __launch_bounds__(256, 3)
void conv_max_kernel(const float* __restrict__ x, const u16* __restrict__ wu,
                     const float* __restrict__ b3, const float* __restrict__ b4,
                     const float* __restrict__ b5, float* __restrict__ feats) {
  __shared__ __align__(16) u16 xs[68 * 320];   // rows s0-2 .. s0+65, 640 B row stride
  const int bid = blockIdx.x;
  const int b = bid >> 1, s0 = (bid & 1) * 64;
  const int tid = threadIdx.x;
  const float* xb = x + (size_t)b * (SEQ * EMB);

  // stage x tile: fp32 -> bf16, zero pad (rows outside [0,128), cols 300..319), swizzled
  for (int t = tid; t < 68 * 80; t += 256) {
    int r = t / 80, cg = t - r * 80;
    int xr = s0 - 2 + r;
    float4 v = make_float4(0.f, 0.f, 0.f, 0.f);
    if (xr >= 0 && xr < SEQ && cg < 75)
      v = *reinterpret_cast<const float4*>(xb + xr * EMB + cg * 4);
    ushort4 h;
    h.x = f2bf(v.x); h.y = f2bf(v.y); h.z = f2bf(v.z); h.w = f2bf(v.w);
    int boff = (r * 640 + cg * 8) ^ ((r & 7) << 4);
    *reinterpret_cast<ushort4*>((char*)xs + boff) = h;
  }
  __syncthreads();

  const int l = tid & 63, w = tid >> 6;
  const int lo = l & 15, hi = l >> 4;
  const int wm = w >> 1, wn = w & 1;

  f32x4 acc[2][10];
  #pragma unroll
  for (int m = 0; m < 2; ++m)
    #pragma unroll
    for (int j = 0; j < 10; ++j) acc[m][j] = (f32x4){0.f, 0.f, 0.f, 0.f};

  const u16* wb = wu + (wn * 10) * 512 + l * 8;
  const int arow0 = wm * 32 + lo;                 // + m*16 + dk -> xs row

  #pragma unroll
  for (int dk = 0; dk < 5; ++dk) {
    #pragma unroll 2
    for (int eg = 0; eg < 10; ++eg) {
      const int kt = dk * 10 + eg;
      bf16x8 bb[10];
      #pragma unroll
      for (int j = 0; j < 10; ++j)
        bb[j] = *reinterpret_cast<const bf16x8*>(wb + (size_t)kt * (NT_TOT * 512) + j * 512);
      bf16x8 aa[2];
      #pragma unroll
      for (int m = 0; m < 2; ++m) {
        int row  = arow0 + m * 16 + dk;
        int boff = (row * 640 + eg * 64 + hi * 16) ^ ((row & 7) << 4);
        aa[m] = *reinterpret_cast<const bf16x8*>((const char*)xs + boff);
      }
      #pragma unroll
      for (int m = 0; m < 2; ++m)
        #pragma unroll
        for (int j = 0; j < 10; ++j)
          acc[m][j] = __builtin_amdgcn_mfma_f32_16x16x32_bf16(aa[m], bb[j], acc[m][j], 0, 0, 0);
    }
  }

  // epilogue: bias + relu + masked max over this block's 64 s-positions
  #pragma unroll
  for (int j = 0; j < 10; ++j) {
    int f = (wn * 10 + j) * 16 + lo;
    if (f < 300) {
      float bia  = (f < 100) ? b3[f] : (f < 200) ? b4[f - 100] : b5[f - 200];
      int   sval = (f < 100) ? 126   : (f < 200) ? 127         : 128;
      float cmax = 0.f;                            // relu floor
      #pragma unroll
      for (int m = 0; m < 2; ++m)
        #pragma unroll
        for (int ii = 0; ii < 4; ++ii) {
          int s = s0 + wm * 32 + m * 16 + hi * 4 + ii;   // C/D: row=(l>>4)*4+ii, col=l&15
          float v = acc[m][j][ii] + bia;
          if (s < sval) cmax = fmaxf(cmax, v);
        }
      cmax = fmaxf(cmax, __shfl_xor(cmax, 16));
      cmax = fmaxf(cmax, __shfl_xor(cmax, 32));
      if (hi == 0)
        atomicMax((int*)&feats[b * 300 + f], __float_as_int(fmaxf(cmax, 0.f)));
    }
  }
}

// feats[512,300] @ Wfc[5,300]^T + bfc -> log_softmax. One wave per row.
__global__ void fc_kernel(const float* __restrict__ feats, const float* __restrict__ Wfc,
                          const float* __restrict__ bfc, float* __restrict__ out) {
  const int b = blockIdx.x, l = threadIdx.x;
  float acc[5] = {0.f, 0.f, 0.f, 0.f, 0.f};
  for (int e = l; e < 300; e += 64) {
    float fv = feats[b * 300 + e];
    #pragma unroll
    for (int c = 0; c < 5; ++c) acc[c] += fv * Wfc[c * 300 + e];
  }
  #pragma unroll
  for (int off = 32; off; off >>= 1) {
    #pragma unroll
    for (int c = 0; c < 5; ++c) acc[c] += __shfl_down(acc[c], off);
  }
  if (l == 0) {
    float lg[5], m = -1e30f;
    #pragma unroll
    for (int c = 0; c < 5; ++c) { lg[c] = acc[c] + bfc[c]; m = fmaxf(m, lg[c]); }
    float se = 0.f;
    #pragma unroll
    for (int c = 0; c < 5; ++c) se += expf(lg[c] - m);
    float ls = logf(se);
    #pragma unroll
    for (int c = 0; c < 5; ++c) out[b * 5 + c] = lg[c] - m - ls;
  }
}

extern "C" void kernel_launch(void* const* d_in, const int* in_sizes, int n_in,
                              void* d_out, int out_size, void* d_ws, size_t ws_size,
                              hipStream_t stream) {
  const float* x   = (const float*)d_in[0];
  const float* w3  = (const float*)d_in[1];
  const float* b3  = (const float*)d_in[2];
  const float* w4  = (const float*)d_in[3];
  const float* b4  = (const float*)d_in[4];
  const float* w5  = (const float*)d_in[5];
  const float* b5  = (const float*)d_in[6];
  const float* Wfc = (const float*)d_in[7];
  const float* bfc = (const float*)d_in[8];
  float* out = (float*)d_out;

  u16*   wu    = (u16*)d_ws;
  float* feats = (float*)((char*)d_ws + OFF_FEATS);

  hipMemsetAsync(feats, 0, NB * 300 * sizeof(float), stream);  // atomicMax target

  prep_weights<<<(WU_ELEMS + 255) / 256, 256, 0, stream>>>(w3, w4, w5, wu);
  conv_max_kernel<<<NB * 2, 256, 0, stream>>>(x, wu, b3, b4, b5, feats);
  fc_kernel<<<NB, 64, 0, stream>>>(feats, Wfc, bfc, out);
}

// Round 4
// 91.660 us; speedup vs baseline: 1.9013x; 1.1015x over previous
//
#include <hip/hip_runtime.h>

typedef __bf16 bf16x8 __attribute__((ext_vector_type(8)));
typedef float  f32x4  __attribute__((ext_vector_type(4)));
typedef unsigned short u16;

#define NB    512
#define SEQ   128
#define EMB   300
#define NT_TOT 20               // N = 320 unified (300 filters padded), tiles of 16
#define KT_TOT 50               // K = 1600 = 50*32
#define WU_ELEMS (320 * 1600)   // 512000 bf16
#define OFF_FEATS (WU_ELEMS * 2)

// LDS layout: A tile (132 rows x 320 bf16, 640B stride) + 2 B slots (20KB each)
#define A_BYTES (132 * 640)     // 84480
#define B_SLOT  (NT_TOT * 1024) // 20480 bytes = one K-step of all 20 N-tiles

// async global->LDS, 16B per lane; LDS dest = uniform base + lane*16 (linear)
#define GLOAD16(gsrc, ldst)                                                    \
  __builtin_amdgcn_global_load_lds(                                            \
      (const __attribute__((address_space(1))) unsigned int*)(gsrc),           \
      (__attribute__((address_space(3))) unsigned int*)(ldst), 16, 0, 0)

__device__ __forceinline__ u16 f2bf(float f) {
  unsigned u = __builtin_bit_cast(unsigned, f);
  return (u16)((u + 0x7fffu + ((u >> 16) & 1u)) >> 16);   // RNE
}

// Unified weights, MFMA-B-fragment order, kt-major:
//   elem idx = ((kt*20 + nt)*64 + lane)*8 + j
//   -> W[f = nt*16 + (lane&15)][kk = kt*32 + (lane>>4)*8 + j]
// kk -> (dk = kk/320, e = kk%320); window rows aligned to k=5 (x rows s-2..s+2):
//   f<100: w3 valid dk 2..4 ; f<200: w4 valid dk 1..4 ; f<300: w5 dk 0..4
__global__ void prep_weights(const float* __restrict__ w3, const float* __restrict__ w4,
                             const float* __restrict__ w5, u16* __restrict__ wu) {
  int idx = blockIdx.x * blockDim.x + threadIdx.x;
  if (idx >= WU_ELEMS) return;
  int j = idx & 7, l = (idx >> 3) & 63, t = idx >> 9;
  int nt = t % NT_TOT, kt = t / NT_TOT;
  int f  = nt * 16 + (l & 15);
  int kk = kt * 32 + ((l >> 4) << 3) + j;
  int dk = kk / 320, e = kk - dk * 320;
  float v = 0.f;
  if (f < 300 && e < 300) {
    if (f < 100)      { if (dk >= 2) v = w3[(f * 3 + dk - 2) * 300 + e]; }
    else if (f < 200) { if (dk >= 1) v = w4[((f - 100) * 4 + dk - 1) * 300 + e]; }
    else              {              v = w5[((f - 200) * 5 + dk) * 300 + e]; }
  }
  wu[idx] = f2bf(v);
}

// Block = one full sample: M=128, N=320, K=1600. 512 thr = 8 waves (wm 0-1 x wn 0-3);
// wave = 4 M-tiles x 5 N-tiles (20 MFMA/K-step). A staged once in LDS (swizzled);
// B double-buffered via global_load_lds (20KB/K-step shared by all 8 waves).
__global__ __launch_bounds__(512, 2)
void conv_max_kernel(const float* __restrict__ x, const u16* __restrict__ wu,
                     const float* __restrict__ b3, const float* __restrict__ b4,
                     const float* __restrict__ b5, float* __restrict__ feats) {
  __shared__ __align__(16) char smem[A_BYTES + 2 * B_SLOT];   // 122.5 KB
  u16*  xs = (u16*)smem;
  char* Bs = smem + A_BYTES;

  const int b   = blockIdx.x;
  const int tid = threadIdx.x;
  const int l = tid & 63, w = tid >> 6;
  const int lo = l & 15, hi = l >> 4;
  const int wm = w >> 2, wn = w & 3;
  const float* xb = x + (size_t)b * (SEQ * EMB);
  const char*  wB = (const char*)wu;

  // issue B stage for kt=0 into slot 0 (flies during A staging)
  {
    const char* g = wB;
    GLOAD16(g + w * 1024 + l * 16, Bs + w * 1024);
    GLOAD16(g + (w + 8) * 1024 + l * 16, Bs + (w + 8) * 1024);
    if (w < 4) GLOAD16(g + (w + 16) * 1024 + l * 16, Bs + (w + 16) * 1024);
  }

  // stage A: rows -2..129 (132), cols 0..319 bf16, 640B stride, XOR swizzle (r1-verified)
  for (int t = tid; t < 132 * 80; t += 512) {
    int r = t / 80, cg = t - r * 80;
    int xr = r - 2;
    float4 v = make_float4(0.f, 0.f, 0.f, 0.f);
    if (xr >= 0 && xr < SEQ && cg < 75)
      v = *reinterpret_cast<const float4*>(xb + xr * EMB + cg * 4);
    ushort4 h;
    h.x = f2bf(v.x); h.y = f2bf(v.y); h.z = f2bf(v.z); h.w = f2bf(v.w);
    int boff = (r * 640 + cg * 8) ^ ((r & 7) << 4);
    *reinterpret_cast<ushort4*>(smem + boff) = h;
  }
  __syncthreads();   // drains vmcnt too: B slot 0 ready

  f32x4 acc[4][5];
  #pragma unroll
  for (int mt = 0; mt < 4; ++mt)
    #pragma unroll
    for (int j = 0; j < 5; ++j) acc[mt][j] = (f32x4){0.f, 0.f, 0.f, 0.f};

  const int wmbase = wm * 64;
  int dk = 0, eg = 0;
  for (int kt = 0; kt < KT_TOT; ++kt) {
    const int slot = kt & 1;
    // prefetch B[kt+1] into the other slot (latency hides under this step's MFMAs)
    if (kt < KT_TOT - 1) {
      const char* g = wB + (size_t)(kt + 1) * B_SLOT;
      char* d = Bs + (slot ^ 1) * B_SLOT;
      GLOAD16(g + w * 1024 + l * 16, d + w * 1024);
      GLOAD16(g + (w + 8) * 1024 + l * 16, d + (w + 8) * 1024);
      if (w < 4) GLOAD16(g + (w + 16) * 1024 + l * 16, d + (w + 16) * 1024);
    }

    const char* bs = Bs + slot * B_SLOT + (wn * 5) * 1024 + l * 16;
    bf16x8 bb[5];
    #pragma unroll
    for (int j = 0; j < 5; ++j)
      bb[j] = *reinterpret_cast<const bf16x8*>(bs + j * 1024);

    bf16x8 aa[4];
    #pragma unroll
    for (int mt = 0; mt < 4; ++mt) {
      int row  = wmbase + mt * 16 + lo + dk;
      int boff = (row * 640 + eg * 64 + hi * 16) ^ ((row & 7) << 4);
      aa[mt] = *reinterpret_cast<const bf16x8*>(smem + boff);
    }

    #pragma unroll
    for (int mt = 0; mt < 4; ++mt)
      #pragma unroll
      for (int j = 0; j < 5; ++j)
        acc[mt][j] = __builtin_amdgcn_mfma_f32_16x16x32_bf16(aa[mt], bb[j], acc[mt][j], 0, 0, 0);

    __syncthreads();   // slot ping-pong boundary
    if (++eg == 10) { eg = 0; ++dk; }
  }

  // epilogue: bias + relu + masked max over the sample's 128 s-positions
  #pragma unroll
  for (int j = 0; j < 5; ++j) {
    int f = (wn * 5 + j) * 16 + lo;
    if (f < 300) {
      float bia  = (f < 100) ? b3[f] : (f < 200) ? b4[f - 100] : b5[f - 200];
      int   sval = (f < 100) ? 126   : (f < 200) ? 127         : 128;
      float cmax = 0.f;                            // relu floor
      #pragma unroll
      for (int mt = 0; mt < 4; ++mt)
        #pragma unroll
        for (int ii = 0; ii < 4; ++ii) {
          int s = wmbase + mt * 16 + hi * 4 + ii;  // C/D: row=(l>>4)*4+ii, col=l&15
          float v = acc[mt][j][ii] + bia;
          if (s < sval) cmax = fmaxf(cmax, v);
        }
      cmax = fmaxf(cmax, __shfl_xor(cmax, 16));
      cmax = fmaxf(cmax, __shfl_xor(cmax, 32));
      if (hi == 0)
        atomicMax((int*)&feats[b * 300 + f], __float_as_int(fmaxf(cmax, 0.f)));
    }
  }
}

// feats[512,300] @ Wfc[5,300]^T + bfc -> log_softmax. One wave per row.
__global__ void fc_kernel(const float* __restrict__ feats, const float* __restrict__ Wfc,
                          const float* __restrict__ bfc, float* __restrict__ out) {
  const int b = blockIdx.x, l = threadIdx.x;
  float acc[5] = {0.f, 0.f, 0.f, 0.f, 0.f};
  for (int e = l; e < 300; e += 64) {
    float fv = feats[b * 300 + e];
    #pragma unroll
    for (int c = 0; c < 5; ++c) acc[c] += fv * Wfc[c * 300 + e];
  }
  #pragma unroll
  for (int off = 32; off; off >>= 1) {
    #pragma unroll
    for (int c = 0; c < 5; ++c) acc[c] += __shfl_down(acc[c], off);
  }
  if (l == 0) {
    float lg[5], m = -1e30f;
    #pragma unroll
    for (int c = 0; c < 5; ++c) { lg[c] = acc[c] + bfc[c]; m = fmaxf(m, lg[c]); }
    float se = 0.f;
    #pragma unroll
    for (int c = 0; c < 5; ++c) se += expf(lg[c] - m);
    float ls = logf(se);
    #pragma unroll
    for (int c = 0; c < 5; ++c) out[b * 5 + c] = lg[c] - m - ls;
  }
}

extern "C" void kernel_launch(void* const* d_in, const int* in_sizes, int n_in,
                              void* d_out, int out_size, void* d_ws, size_t ws_size,
                              hipStream_t stream) {
  const float* x   = (const float*)d_in[0];
  const float* w3  = (const float*)d_in[1];
  const float* b3  = (const float*)d_in[2];
  const float* w4  = (const float*)d_in[3];
  const float* b4  = (const float*)d_in[4];
  const float* w5  = (const float*)d_in[5];
  const float* b5  = (const float*)d_in[6];
  const float* Wfc = (const float*)d_in[7];
  const float* bfc = (const float*)d_in[8];
  float* out = (float*)d_out;

  u16*   wu    = (u16*)d_ws;
  float* feats = (float*)((char*)d_ws + OFF_FEATS);

  hipMemsetAsync(feats, 0, NB * 300 * sizeof(float), stream);  // atomicMax target

  prep_weights<<<(WU_ELEMS + 255) / 256, 256, 0, stream>>>(w3, w4, w5, wu);
  conv_max_kernel<<<NB, 512, 0, stream>>>(x, wu, b3, b4, b5, feats);
  fc_kernel<<<NB, 64, 0, stream>>>(feats, Wfc, bfc, out);
}